// Round 5
// baseline (289.815 us; speedup 1.0000x reference)
//
#include <hip/hip_runtime.h>
#include <hip/hip_cooperative_groups.h>
#include <math.h>

namespace cg = cooperative_groups;

#define T_SEQ 2048
#define NH    12
#define NB    2
#define BHC   (NB*NH)        // 24
#define NQT   32             // 2048/64

typedef _Float16 half4_t __attribute__((ext_vector_type(4)));
typedef _Float16 half8_t __attribute__((ext_vector_type(8)));
typedef float    floatx4 __attribute__((ext_vector_type(4)));

__device__ __forceinline__ void async_cp16(const void* g, void* l) {
  __builtin_amdgcn_global_load_lds((const __attribute__((address_space(1))) void*)g,
                                   (__attribute__((address_space(3))) void*)l, 16, 0, 0);
}
__device__ __forceinline__ void async_cp4(const void* g, void* l) {
  __builtin_amdgcn_global_load_lds((const __attribute__((address_space(1))) void*)g,
                                   (__attribute__((address_space(3))) void*)l, 4, 0, 0);
}
__device__ __forceinline__ half8_t h8splat(_Float16 s) {
  return (half8_t){s, s, s, s, s, s, s, s};
}

// One cooperative kernel: phase 1 = prep (frag-order f16 Q_aug/K_aug/V to ws),
// grid sync, phase 2 = flash (S^T trick, single-buffer async staging).
__global__ __launch_bounds__(256, 3) void fused_kernel(
    const float* __restrict__ Q, const float* __restrict__ K,
    const float* __restrict__ V, const float* __restrict__ dbias,
    const float* __restrict__ W, const float* __restrict__ wstd,
    const float* __restrict__ wrec, const float* __restrict__ wdisc,
    ushort* __restrict__ QF, ushort* __restrict__ KF, ushort* __restrict__ VF,
    float* __restrict__ Out)
{
  // phase-1 layout: Qsh/Ksh/Vsh [64*72] f16, Lqh/Lkh [64*16] f16  (31744 B)
  // phase-2 layout: KsL [4096] u16, VsL [4096] u16, bs [64] f32   (16640 B)
  __shared__ __align__(16) char smem[31744];

  const int tid = threadIdx.x;
  const int w = tid >> 6, lane = tid & 63;
  const int quad = lane >> 4, ln = lane & 15;

  // ================= phase 1: prep =================
  {
    _Float16* Qsh = (_Float16*)smem;            // stride 72 (144B rows)
    _Float16* Ksh = (_Float16*)(smem + 9216);
    _Float16* Vsh = (_Float16*)(smem + 18432);
    _Float16* Lqh = (_Float16*)(smem + 27648);  // [64*16]
    _Float16* Lkh = (_Float16*)(smem + 29696);

    const int bh = blockIdx.x >> 5, tblk = blockIdx.x & 31;
    const long g0 = ((long)bh * T_SEQ + tblk * 64) * 64;

    const float4* gQ = (const float4*)(Q + g0);
    const float4* gK = (const float4*)(K + g0);
    const float4* gV = (const float4*)(V + g0);
    for (int i = tid; i < 1024; i += 256) {
      int r = i >> 4, c4 = i & 15;
      float4 q = gQ[i], k = gK[i], v = gV[i];
      *(half4_t*)&Qsh[r*72 + c4*4] = (half4_t){(_Float16)q.x,(_Float16)q.y,(_Float16)q.z,(_Float16)q.w};
      *(half4_t*)&Ksh[r*72 + c4*4] = (half4_t){(_Float16)k.x,(_Float16)k.y,(_Float16)k.z,(_Float16)k.w};
      *(half4_t*)&Vsh[r*72 + c4*4] = (half4_t){(_Float16)v.x,(_Float16)v.y,(_Float16)v.z,(_Float16)v.w};
    }
    __syncthreads();

    // W B-frags from global (4KB, L2-resident)
    half4_t bw[4];
#pragma unroll
    for (int dk = 0; dk < 4; dk++)
#pragma unroll
      for (int i = 0; i < 4; i++)
        bw[dk][i] = (_Float16)W[(dk*16 + quad*4 + i)*16 + ln];

    // Q_low = Q·W, K_low = K·W (wave w owns rows 16w..16w+15)
    floatx4 cq = {0.f,0.f,0.f,0.f}, ck = {0.f,0.f,0.f,0.f};
#pragma unroll
    for (int dk = 0; dk < 4; dk++) {
      half4_t aq = *(const half4_t*)&Qsh[(w*16 + ln)*72 + dk*16 + quad*4];
      half4_t ak = *(const half4_t*)&Ksh[(w*16 + ln)*72 + dk*16 + quad*4];
      cq = __builtin_amdgcn_mfma_f32_16x16x16f16(aq, bw[dk], cq, 0, 0, 0);
      ck = __builtin_amdgcn_mfma_f32_16x16x16f16(ak, bw[dk], ck, 0, 0, 0);
    }
#pragma unroll
    for (int i = 0; i < 4; i++) {            // C: row = 16w+quad*4+i, col = ln
      Lqh[(w*16 + quad*4 + i)*16 + ln] = (_Float16)cq[i];
      Lkh[(w*16 + quad*4 + i)*16 + ln] = (_Float16)ck[i];
    }
    __syncthreads();

    const int h = bh % NH;
    const float sstd = sqrtf(wstd[h]);
    const float srec = sqrtf(wrec[h]);
    const half8_t hq_std = h8splat((_Float16)(0.125f * sstd));  // 1/sqrt(64) folded
    const half8_t hk_std = h8splat((_Float16)sstd);
    const half8_t hq_rec = h8splat((_Float16)(0.125f * srec));
    const half8_t hk_rec = h8splat((_Float16)srec);

#pragma unroll
    for (int cc = 0; cc < 2; cc++) {
      int c = tid + cc * 256;                // chunk 0..511
      // ---- QF / KF (x32 frag order: row = tile16*16+ln, d = dp*32+quad*8+j) ----
      {
        int lp = c & 63, dp = (c >> 6) & 1, rt = c >> 7;
        int row = rt*16 + (lp & 15);
        int d0 = dp*32 + (lp >> 4)*8;        // 48-boundary falls on chunk boundary
        half8_t hq, hk;
        if (d0 < 48) {
          hq = *(const half8_t*)&Qsh[row*72 + d0] * hq_std;
          hk = *(const half8_t*)&Ksh[row*72 + d0] * hk_std;
        } else {
          hq = *(const half8_t*)&Lkh[row*16 + (d0-48)] * hq_rec;  // Q_aug gets K_low
          hk = *(const half8_t*)&Lqh[row*16 + (d0-48)] * hk_rec;  // K_aug gets Q_low
        }
        long tile16 = (long)bh*128 + tblk*4 + rt;
        ((int4*)QF)[tile16*128 + dp*64 + lp] = *(int4*)&hq;
        ((int4*)KF)[tile16*128 + dp*64 + lp] = *(int4*)&hk;
      }
      // ---- VF (x16 frag order: d = nt*16+ln, key = v2*32+quad*4+{j,16+j}) ----
      {
        int lv = c & 63, nt = (c >> 6) & 3, v2 = c >> 8;
        int d = nt*16 + (lv & 15), qv = lv >> 4;
        half8_t hv;
#pragma unroll
        for (int j = 0; j < 4; j++) {
          hv[j]   = Vsh[(v2*32 + qv*4 + j)*72 + d];
          hv[4+j] = Vsh[(v2*32 + 16 + qv*4 + j)*72 + d];
        }
        ((int4*)VF)[((long)bh*32 + tblk)*512 + (v2*4 + nt)*64 + lv] = *(int4*)&hv;
      }
    }
  }

  __threadfence();          // release ws writes device-wide (cross-XCD)
  cg::this_grid().sync();   // all prep done before any flash reads

  // ================= phase 2: flash =================
  {
    ushort* KsL = (ushort*)smem;            // [4096] frag order
    ushort* VsL = (ushort*)(smem + 8192);   // [4096]
    float*  bs  = (float*)(smem + 16384);   // [64]

    const int bid = blockIdx.x;
    const int bh = bid % BHC;               // same bh -> same XCD (24 % 8 == 0)
    const int qt = NQT - 1 - bid / BHC;     // heavy tiles first
    const int h = bh % NH;
    const int q0 = qt * 64;
    const int qrow = q0 + w*16 + ln;        // this lane's q-row
    const float wd = wdisc[h];

    const ushort* gKb = KF + (long)bh * 131072;
    const ushort* gVb = VF + (long)bh * 131072;
    const float*  gB  = dbias + (long)bh * T_SEQ;

    // Q B-frags (x32 layout), whole K-loop in regs
    half8_t bq[2];
    {
      const ushort* gQ = QF + ((long)bh*128 + qt*4 + w) * 1024;
      bq[0] = *(const half8_t*)(gQ + lane*8);
      bq[1] = *(const half8_t*)(gQ + 512 + lane*8);
    }

    float m_i = -1e30f, l_i = 0.f;
    floatx4 acc[4];
#pragma unroll
    for (int nt = 0; nt < 4; nt++) acc[nt] = (floatx4){0.f,0.f,0.f,0.f};

    for (int kt = 0; kt <= qt; kt++) {
      __syncthreads();   // all waves done reading previous tile
      {
        const long o = (long)kt * 4096;
        for (int c = w; c < 8; c += 4) {
          async_cp16(gKb + o + c*512 + lane*8, &KsL[c*512]);  // dest = base + lane*16
          async_cp16(gVb + o + c*512 + lane*8, &VsL[c*512]);
        }
        if (w == 0) async_cp4(gB + kt*64 + lane, bs);
      }
      __syncthreads();   // structural vmcnt(0) drain before barrier

      // ---- S^T = K_aug·Q_aug^T (x32): st[mt][i] = S[q=ln][key=kt*64+mt*16+quad*4+i]
      floatx4 st[4];
#pragma unroll
      for (int mt = 0; mt < 4; mt++) st[mt] = (floatx4){0.f,0.f,0.f,0.f};
#pragma unroll
      for (int mt = 0; mt < 4; mt++)
#pragma unroll
        for (int dp = 0; dp < 2; dp++) {
          half8_t a = *(const half8_t*)&KsL[(mt*2 + dp)*512 + lane*8];
          st[mt] = __builtin_amdgcn_mfma_f32_16x16x32_f16(a, bq[dp], st[mt], 0, 0, 0);
        }

      // ---- bias + causal mask + online softmax (one q-row per lane) ----
      const bool diag = (kt == qt);
      float rowmax = -1e30f;
#pragma unroll
      for (int mt = 0; mt < 4; mt++)
#pragma unroll
        for (int i = 0; i < 4; i++) {
          float v = st[mt][i] + wd * bs[mt*16 + quad*4 + i];
          int key = kt*64 + mt*16 + quad*4 + i;
          if (diag && key > qrow) v = -1e30f;
          st[mt][i] = v;
          rowmax = fmaxf(rowmax, v);
        }
      rowmax = fmaxf(rowmax, __shfl_xor(rowmax, 16));
      rowmax = fmaxf(rowmax, __shfl_xor(rowmax, 32));
      float mnew  = fmaxf(m_i, rowmax);
      float alpha = __expf(m_i - mnew);
      float psum = 0.f;
      half4_t pa[4];                        // C-regs are directly the x16 PV A-operand
#pragma unroll
      for (int mt = 0; mt < 4; mt++)
#pragma unroll
        for (int i = 0; i < 4; i++) {
          float p = __expf(st[mt][i] - mnew);
          psum += p;
          pa[mt][i] = (_Float16)p;
        }
      psum += __shfl_xor(psum, 16);
      psum += __shfl_xor(psum, 32);
      l_i = l_i * alpha + psum;
      m_i = mnew;

      float af[4];
#pragma unroll
      for (int i = 0; i < 4; i++) af[i] = __shfl(alpha, quad*4 + i);
#pragma unroll
      for (int nt = 0; nt < 4; nt++)
#pragma unroll
        for (int i = 0; i < 4; i++) acc[nt][i] *= af[i];

      // ---- O += P·V (x16; P never touches LDS) ----
#pragma unroll
      for (int v2 = 0; v2 < 2; v2++)
#pragma unroll
        for (int nt = 0; nt < 4; nt++) {
          half8_t vv = *(const half8_t*)&VsL[(v2*4 + nt)*512 + lane*8];
          half4_t b0 = __builtin_shufflevector(vv, vv, 0,1,2,3);
          half4_t b1 = __builtin_shufflevector(vv, vv, 4,5,6,7);
          acc[nt] = __builtin_amdgcn_mfma_f32_16x16x16f16(pa[2*v2],   b0, acc[nt], 0, 0, 0);
          acc[nt] = __builtin_amdgcn_mfma_f32_16x16x16f16(pa[2*v2+1], b1, acc[nt], 0, 0, 0);
        }
    }

    // ---- epilogue ----
    float lr[4];
#pragma unroll
    for (int i = 0; i < 4; i++) lr[i] = 1.f / __shfl(l_i, quad*4 + i);
    const long obase = (long)bh*T_SEQ*64 + (long)(q0 + w*16)*64;
#pragma unroll
    for (int i = 0; i < 4; i++)
#pragma unroll
      for (int nt = 0; nt < 4; nt++)
        Out[obase + (quad*4 + i)*64 + nt*16 + ln] = acc[nt][i] * lr[i];
  }
}

extern "C" void kernel_launch(void* const* d_in, const int* in_sizes, int n_in,
                              void* d_out, int out_size, void* d_ws, size_t ws_size,
                              hipStream_t stream) {
  const float* Q     = (const float*)d_in[0];
  const float* K     = (const float*)d_in[1];
  const float* V     = (const float*)d_in[2];
  const float* dbias = (const float*)d_in[3];
  const float* W     = (const float*)d_in[4];
  const float* wstd  = (const float*)d_in[5];
  const float* wrec  = (const float*)d_in[6];
  const float* wdisc = (const float*)d_in[7];
  float* Out = (float*)d_out;

  const long NEL = (long)BHC * T_SEQ * 64;
  ushort* QF = (ushort*)d_ws;    // f16 x32-frag-order Q_aug (scales folded)
  ushort* KF = QF + NEL;         // f16 x32-frag-order K_aug
  ushort* VF = KF + NEL;         // f16 x16-frag-order V

  void* args[] = { (void*)&Q, (void*)&K, (void*)&V, (void*)&dbias, (void*)&W,
                   (void*)&wstd, (void*)&wrec, (void*)&wdisc,
                   (void*)&QF, (void*)&KF, (void*)&VF, (void*)&Out };
  hipLaunchCooperativeKernel((const void*)fused_kernel, dim3(BHC * NQT), dim3(256),
                             args, 0, stream);
}

// Round 6
// 136.731 us; speedup vs baseline: 2.1196x; 2.1196x over previous
//
#include <hip/hip_runtime.h>
#include <math.h>

#define T_SEQ 2048
#define NH    12
#define NB    2
#define BHC   (NB*NH)        // 24
#define NQT   32             // 2048/64

typedef _Float16 half4_t __attribute__((ext_vector_type(4)));
typedef _Float16 half8_t __attribute__((ext_vector_type(8)));
typedef float    floatx4 __attribute__((ext_vector_type(4)));

__device__ __forceinline__ void async_cp16(const void* g, void* l) {
  __builtin_amdgcn_global_load_lds((const __attribute__((address_space(1))) void*)g,
                                   (__attribute__((address_space(3))) void*)l, 16, 0, 0);
}
__device__ __forceinline__ void async_cp4(const void* g, void* l) {
  __builtin_amdgcn_global_load_lds((const __attribute__((address_space(1))) void*)g,
                                   (__attribute__((address_space(3))) void*)l, 4, 0, 0);
}
__device__ __forceinline__ half8_t h8splat(_Float16 s) {
  return (half8_t){s, s, s, s, s, s, s, s};
}

// ---------------- prep (R4 form — ~10 µs class) ----------------
// QF/KF chunk (tile16, dp, lane): row = tile16*16 + ln, d = dp*32 + quad*8 + j  (x32 frag order)
// VF chunk (tile64, v2, nt, lane): d = nt*16 + ln, key = tile64*64 + v2*32 + quad*4 + {j, 16+j} (x16)
__global__ __launch_bounds__(256) void prep_kernel(
    const float* __restrict__ Q, const float* __restrict__ K,
    const float* __restrict__ V, const float* __restrict__ W,
    const float* __restrict__ wstd, const float* __restrict__ wrec,
    ushort* __restrict__ QF, ushort* __restrict__ KF, ushort* __restrict__ VF)
{
  __shared__ __align__(16) _Float16 Qsh[64*72];   // 144B row stride
  __shared__ __align__(16) _Float16 Ksh[64*72];
  __shared__ __align__(16) _Float16 Vsh[64*72];
  __shared__ __align__(16) _Float16 Lqh[64*16];
  __shared__ __align__(16) _Float16 Lkh[64*16];

  const int tid = threadIdx.x;
  const int w = tid >> 6, lane = tid & 63;
  const int quad = lane >> 4, ln = lane & 15;
  const int bh = blockIdx.x >> 5, tblk = blockIdx.x & 31;
  const long g0 = ((long)bh * T_SEQ + tblk * 64) * 64;

  const float4* gQ = (const float4*)(Q + g0);
  const float4* gK = (const float4*)(K + g0);
  const float4* gV = (const float4*)(V + g0);
  for (int i = tid; i < 1024; i += 256) {
    int r = i >> 4, c4 = i & 15;
    float4 q = gQ[i], k = gK[i], v = gV[i];
    *(half4_t*)&Qsh[r*72 + c4*4] = (half4_t){(_Float16)q.x,(_Float16)q.y,(_Float16)q.z,(_Float16)q.w};
    *(half4_t*)&Ksh[r*72 + c4*4] = (half4_t){(_Float16)k.x,(_Float16)k.y,(_Float16)k.z,(_Float16)k.w};
    *(half4_t*)&Vsh[r*72 + c4*4] = (half4_t){(_Float16)v.x,(_Float16)v.y,(_Float16)v.z,(_Float16)v.w};
  }
  __syncthreads();

  half4_t bw[4];
#pragma unroll
  for (int dk = 0; dk < 4; dk++)
#pragma unroll
    for (int i = 0; i < 4; i++)
      bw[dk][i] = (_Float16)W[(dk*16 + quad*4 + i)*16 + ln];

  floatx4 cq = {0.f,0.f,0.f,0.f}, ck = {0.f,0.f,0.f,0.f};
#pragma unroll
  for (int dk = 0; dk < 4; dk++) {
    half4_t aq = *(const half4_t*)&Qsh[(w*16 + ln)*72 + dk*16 + quad*4];
    half4_t ak = *(const half4_t*)&Ksh[(w*16 + ln)*72 + dk*16 + quad*4];
    cq = __builtin_amdgcn_mfma_f32_16x16x16f16(aq, bw[dk], cq, 0, 0, 0);
    ck = __builtin_amdgcn_mfma_f32_16x16x16f16(ak, bw[dk], ck, 0, 0, 0);
  }
#pragma unroll
  for (int i = 0; i < 4; i++) {            // C: row = 16w+quad*4+i, col = ln
    Lqh[(w*16 + quad*4 + i)*16 + ln] = (_Float16)cq[i];
    Lkh[(w*16 + quad*4 + i)*16 + ln] = (_Float16)ck[i];
  }
  __syncthreads();

  const int h = bh % NH;
  const float sstd = sqrtf(wstd[h]);
  const float srec = sqrtf(wrec[h]);
  const half8_t hq_std = h8splat((_Float16)(0.125f * sstd));  // 1/sqrt(64) folded
  const half8_t hk_std = h8splat((_Float16)sstd);
  const half8_t hq_rec = h8splat((_Float16)(0.125f * srec));
  const half8_t hk_rec = h8splat((_Float16)srec);

#pragma unroll
  for (int cc = 0; cc < 2; cc++) {
    int c = tid + cc * 256;                // chunk 0..511
    {
      int lp = c & 63, dp = (c >> 6) & 1, rt = c >> 7;
      int row = rt*16 + (lp & 15);
      int d0 = dp*32 + (lp >> 4)*8;        // 48-boundary on chunk boundary
      half8_t hq, hk;
      if (d0 < 48) {
        hq = *(const half8_t*)&Qsh[row*72 + d0] * hq_std;
        hk = *(const half8_t*)&Ksh[row*72 + d0] * hk_std;
      } else {
        hq = *(const half8_t*)&Lkh[row*16 + (d0-48)] * hq_rec;  // Q_aug gets K_low
        hk = *(const half8_t*)&Lqh[row*16 + (d0-48)] * hk_rec;  // K_aug gets Q_low
      }
      long tile16 = (long)bh*128 + tblk*4 + rt;
      ((int4*)QF)[tile16*128 + dp*64 + lp] = *(int4*)&hq;
      ((int4*)KF)[tile16*128 + dp*64 + lp] = *(int4*)&hk;
    }
    {
      int lv = c & 63, nt = (c >> 6) & 3, v2 = c >> 8;
      int d = nt*16 + (lv & 15), qv = lv >> 4;
      half8_t hv;
#pragma unroll
      for (int j = 0; j < 4; j++) {
        hv[j]   = Vsh[(v2*32 + qv*4 + j)*72 + d];
        hv[4+j] = Vsh[(v2*32 + 16 + qv*4 + j)*72 + d];
      }
      ((int4*)VF)[((long)bh*32 + tblk)*512 + (v2*4 + nt)*64 + lv] = *(int4*)&hv;
    }
  }
}

// ---------------- flash: S^T trick, single-buffer, K-loop unrolled x2 ----------------
__global__ __launch_bounds__(256) void flash_kernel(
    const ushort* __restrict__ QF, const ushort* __restrict__ KF,
    const ushort* __restrict__ VF, const float* __restrict__ dbias,
    const float* __restrict__ wdisc, float* __restrict__ Out)
{
  __shared__ __align__(16) ushort KsL[8192];   // two 64-key tiles, frag order
  __shared__ __align__(16) ushort VsL[8192];
  __shared__ float bs[128];

  const int tid = threadIdx.x;
  const int w = tid >> 6, lane = tid & 63;
  const int quad = lane >> 4, ln = lane & 15;
  const int bid = blockIdx.x;
  const int bh = bid % BHC;                 // same bh -> same XCD (24 % 8 == 0)
  const int qt = NQT - 1 - bid / BHC;       // heavy tiles first
  const int h = bh % NH;
  const int q0 = qt * 64;
  const int qrow = q0 + w*16 + ln;          // this lane's q-row
  const float wd = wdisc[h];

  const ushort* gKb = KF + (long)bh * 131072;
  const ushort* gVb = VF + (long)bh * 131072;
  const float*  gB  = dbias + (long)bh * T_SEQ;

  // Q B-frags (x32 layout: d = quad*8+j per 32-slice), whole K-loop in regs
  half8_t bq[2];
  {
    const ushort* gQ = QF + ((long)bh*128 + qt*4 + w) * 1024;
    bq[0] = *(const half8_t*)(gQ + lane*8);
    bq[1] = *(const half8_t*)(gQ + 512 + lane*8);
  }

  float m_i = -1e30f, l_i = 0.f;
  floatx4 acc[4];
#pragma unroll
  for (int nt = 0; nt < 4; nt++) acc[nt] = (floatx4){0.f,0.f,0.f,0.f};

  for (int kt0 = 0; kt0 <= qt; kt0 += 2) {
    __syncthreads();   // all waves done reading previous pair
    {
      // stage tiles kt0 and kt0+1 (kt0+1 <= 31 always: when qt==31, kt0 caps at 30)
      const long o = (long)kt0 * 4096;
      for (int c = w; c < 16; c += 4) {
        async_cp16(gKb + o + c*512 + lane*8, &KsL[c*512]);  // dest = base + lane*16
        async_cp16(gVb + o + c*512 + lane*8, &VsL[c*512]);
      }
      if (w < 2) async_cp4(gB + kt0*64 + w*64 + lane, &bs[w*64]);
    }
    __syncthreads();   // structural vmcnt(0) drain

#pragma unroll
    for (int t2 = 0; t2 < 2; t2++) {
      const int kt = kt0 + t2;
      if (kt > qt) break;                  // wave-uniform
      const ushort* Kt = &KsL[t2 * 4096];
      const ushort* Vt = &VsL[t2 * 4096];
      const float*  bt = &bs[t2 * 64];

      // ---- S^T = K_aug·Q_aug^T (x32): st[mt][i] = S[q=ln][key=kt*64+mt*16+quad*4+i]
      floatx4 st[4];
#pragma unroll
      for (int mt = 0; mt < 4; mt++) st[mt] = (floatx4){0.f,0.f,0.f,0.f};
#pragma unroll
      for (int mt = 0; mt < 4; mt++)
#pragma unroll
        for (int dp = 0; dp < 2; dp++) {
          half8_t a = *(const half8_t*)&Kt[(mt*2 + dp)*512 + lane*8];
          st[mt] = __builtin_amdgcn_mfma_f32_16x16x32_f16(a, bq[dp], st[mt], 0, 0, 0);
        }

      // ---- bias + causal mask + online softmax (one q-row per lane) ----
      const bool diag = (kt == qt);
      float rowmax = -1e30f;
#pragma unroll
      for (int mt = 0; mt < 4; mt++)
#pragma unroll
        for (int i = 0; i < 4; i++) {
          float v = st[mt][i] + wd * bt[mt*16 + quad*4 + i];
          int key = kt*64 + mt*16 + quad*4 + i;
          if (diag && key > qrow) v = -1e30f;
          st[mt][i] = v;
          rowmax = fmaxf(rowmax, v);
        }
      rowmax = fmaxf(rowmax, __shfl_xor(rowmax, 16));
      rowmax = fmaxf(rowmax, __shfl_xor(rowmax, 32));
      float mnew  = fmaxf(m_i, rowmax);
      float alpha = __expf(m_i - mnew);
      float psum = 0.f;
      half4_t pa[4];                        // C-regs are directly the x16 PV A-operand
#pragma unroll
      for (int mt = 0; mt < 4; mt++)
#pragma unroll
        for (int i = 0; i < 4; i++) {
          float p = __expf(st[mt][i] - mnew);
          psum += p;
          pa[mt][i] = (_Float16)p;
        }
      psum += __shfl_xor(psum, 16);
      psum += __shfl_xor(psum, 32);
      l_i = l_i * alpha + psum;
      m_i = mnew;

      float af[4];
#pragma unroll
      for (int i = 0; i < 4; i++) af[i] = __shfl(alpha, quad*4 + i);
#pragma unroll
      for (int nt = 0; nt < 4; nt++)
#pragma unroll
        for (int i = 0; i < 4; i++) acc[nt][i] *= af[i];

      // ---- O += P·V (x16; P never touches LDS) ----
#pragma unroll
      for (int v2 = 0; v2 < 2; v2++)
#pragma unroll
        for (int nt = 0; nt < 4; nt++) {
          half8_t vv = *(const half8_t*)&Vt[(v2*4 + nt)*512 + lane*8];
          half4_t b0 = __builtin_shufflevector(vv, vv, 0,1,2,3);
          half4_t b1 = __builtin_shufflevector(vv, vv, 4,5,6,7);
          acc[nt] = __builtin_amdgcn_mfma_f32_16x16x16f16(pa[2*v2],   b0, acc[nt], 0, 0, 0);
          acc[nt] = __builtin_amdgcn_mfma_f32_16x16x16f16(pa[2*v2+1], b1, acc[nt], 0, 0, 0);
        }
    }
  }

  // ---- epilogue ----
  float lr[4];
#pragma unroll
  for (int i = 0; i < 4; i++) lr[i] = 1.f / __shfl(l_i, quad*4 + i);
  const long obase = (long)bh*T_SEQ*64 + (long)(q0 + w*16)*64;
#pragma unroll
  for (int i = 0; i < 4; i++)
#pragma unroll
    for (int nt = 0; nt < 4; nt++)
      Out[obase + (quad*4 + i)*64 + nt*16 + ln] = acc[nt][i] * lr[i];
}

extern "C" void kernel_launch(void* const* d_in, const int* in_sizes, int n_in,
                              void* d_out, int out_size, void* d_ws, size_t ws_size,
                              hipStream_t stream) {
  const float* Q     = (const float*)d_in[0];
  const float* K     = (const float*)d_in[1];
  const float* V     = (const float*)d_in[2];
  const float* dbias = (const float*)d_in[3];
  const float* W     = (const float*)d_in[4];
  const float* wstd  = (const float*)d_in[5];
  const float* wrec  = (const float*)d_in[6];
  const float* wdisc = (const float*)d_in[7];
  float* Out = (float*)d_out;

  const long NEL = (long)BHC * T_SEQ * 64;
  ushort* QF = (ushort*)d_ws;    // f16 x32-frag-order Q_aug (scales folded)
  ushort* KF = QF + NEL;         // f16 x32-frag-order K_aug
  ushort* VF = KF + NEL;         // f16 x16-frag-order V

  prep_kernel<<<BHC * NQT, 256, 0, stream>>>(Q, K, V, W, wstd, wrec, QF, KF, VF);
  flash_kernel<<<BHC * NQT, 256, 0, stream>>>(QF, KF, VF, dbias, wdisc, Out);
}

// Round 7
// 135.316 us; speedup vs baseline: 2.1418x; 1.0105x over previous
//
#include <hip/hip_runtime.h>
#include <math.h>

#define T_SEQ 2048
#define NH    12
#define NB    2
#define BHC   (NB*NH)        // 24
#define NQT   32             // 2048/64

typedef _Float16 half4_t __attribute__((ext_vector_type(4)));
typedef _Float16 half8_t __attribute__((ext_vector_type(8)));
typedef float    floatx4 __attribute__((ext_vector_type(4)));

__device__ __forceinline__ half8_t h8splat(_Float16 s) {
  return (half8_t){s, s, s, s, s, s, s, s};
}

// ---------------- prep: f16 frag-order Q_aug/K_aug/V + premultiplied bias ----------------
// QF/KF chunk (tile16, dp, lane): row = tile16*16 + ln, d = dp*32 + quad*8 + j  (x32 frag order)
// VF chunk (tile64, v2, nt, lane): d = nt*16 + ln, key = tile64*64 + v2*32 + quad*4 + {j,16+j} (x16)
__global__ __launch_bounds__(256) void prep_kernel(
    const float* __restrict__ Q, const float* __restrict__ K,
    const float* __restrict__ V, const float* __restrict__ W,
    const float* __restrict__ wstd, const float* __restrict__ wrec,
    const float* __restrict__ dbias, const float* __restrict__ wdisc,
    ushort* __restrict__ QF, ushort* __restrict__ KF, ushort* __restrict__ VF,
    float* __restrict__ B2)
{
  __shared__ __align__(16) _Float16 Qsh[64*72];   // 144B row stride
  __shared__ __align__(16) _Float16 Ksh[64*72];
  __shared__ __align__(16) _Float16 Vsh[64*72];
  __shared__ __align__(16) _Float16 Lqh[64*16];
  __shared__ __align__(16) _Float16 Lkh[64*16];

  const int tid = threadIdx.x;
  const int w = tid >> 6, lane = tid & 63;
  const int quad = lane >> 4, ln = lane & 15;
  const int bh = blockIdx.x >> 5, tblk = blockIdx.x & 31;
  const long g0 = ((long)bh * T_SEQ + tblk * 64) * 64;

  const float4* gQ = (const float4*)(Q + g0);
  const float4* gK = (const float4*)(K + g0);
  const float4* gV = (const float4*)(V + g0);
  for (int i = tid; i < 1024; i += 256) {
    int r = i >> 4, c4 = i & 15;
    float4 q = gQ[i], k = gK[i], v = gV[i];
    *(half4_t*)&Qsh[r*72 + c4*4] = (half4_t){(_Float16)q.x,(_Float16)q.y,(_Float16)q.z,(_Float16)q.w};
    *(half4_t*)&Ksh[r*72 + c4*4] = (half4_t){(_Float16)k.x,(_Float16)k.y,(_Float16)k.z,(_Float16)k.w};
    *(half4_t*)&Vsh[r*72 + c4*4] = (half4_t){(_Float16)v.x,(_Float16)v.y,(_Float16)v.z,(_Float16)v.w};
  }
  __syncthreads();

  half4_t bw[4];
#pragma unroll
  for (int dk = 0; dk < 4; dk++)
#pragma unroll
    for (int i = 0; i < 4; i++)
      bw[dk][i] = (_Float16)W[(dk*16 + quad*4 + i)*16 + ln];

  floatx4 cq = {0.f,0.f,0.f,0.f}, ck = {0.f,0.f,0.f,0.f};
#pragma unroll
  for (int dk = 0; dk < 4; dk++) {
    half4_t aq = *(const half4_t*)&Qsh[(w*16 + ln)*72 + dk*16 + quad*4];
    half4_t ak = *(const half4_t*)&Ksh[(w*16 + ln)*72 + dk*16 + quad*4];
    cq = __builtin_amdgcn_mfma_f32_16x16x16f16(aq, bw[dk], cq, 0, 0, 0);
    ck = __builtin_amdgcn_mfma_f32_16x16x16f16(ak, bw[dk], ck, 0, 0, 0);
  }
#pragma unroll
  for (int i = 0; i < 4; i++) {            // C: row = 16w+quad*4+i, col = ln
    Lqh[(w*16 + quad*4 + i)*16 + ln] = (_Float16)cq[i];
    Lkh[(w*16 + quad*4 + i)*16 + ln] = (_Float16)ck[i];
  }
  __syncthreads();

  const int h = bh % NH;
  const float sstd = sqrtf(wstd[h]);
  const float srec = sqrtf(wrec[h]);
  const half8_t hq_std = h8splat((_Float16)(0.125f * sstd));  // 1/sqrt(64) folded
  const half8_t hk_std = h8splat((_Float16)sstd);
  const half8_t hq_rec = h8splat((_Float16)(0.125f * srec));
  const half8_t hk_rec = h8splat((_Float16)srec);

  // premultiplied bias
  if (tid < 64) B2[(long)bh*T_SEQ + tblk*64 + tid] =
      wdisc[h] * dbias[(long)bh*T_SEQ + tblk*64 + tid];

#pragma unroll
  for (int cc = 0; cc < 2; cc++) {
    int c = tid + cc * 256;                // chunk 0..511
    {
      int lp = c & 63, dp = (c >> 6) & 1, rt = c >> 7;
      int row = rt*16 + (lp & 15);
      int d0 = dp*32 + (lp >> 4)*8;        // 48-boundary on chunk boundary
      half8_t hq, hk;
      if (d0 < 48) {
        hq = *(const half8_t*)&Qsh[row*72 + d0] * hq_std;
        hk = *(const half8_t*)&Ksh[row*72 + d0] * hk_std;
      } else {
        hq = *(const half8_t*)&Lkh[row*16 + (d0-48)] * hq_rec;  // Q_aug gets K_low
        hk = *(const half8_t*)&Lqh[row*16 + (d0-48)] * hk_rec;  // K_aug gets Q_low
      }
      long tile16 = (long)bh*128 + tblk*4 + rt;
      ((int4*)QF)[tile16*128 + dp*64 + lp] = *(int4*)&hq;
      ((int4*)KF)[tile16*128 + dp*64 + lp] = *(int4*)&hk;
    }
    {
      int lv = c & 63, nt = (c >> 6) & 3, v2 = c >> 8;
      int d = nt*16 + (lv & 15), qv = lv >> 4;
      half8_t hv;
#pragma unroll
      for (int j = 0; j < 4; j++) {
        hv[j]   = Vsh[(v2*32 + qv*4 + j)*72 + d];
        hv[4+j] = Vsh[(v2*32 + 16 + qv*4 + j)*72 + d];
      }
      ((int4*)VF)[((long)bh*32 + tblk)*512 + (v2*4 + nt)*64 + lv] = *(int4*)&hv;
    }
  }
}

// ---------------- flash: one wave per 16-row q-tile, direct-L2 frag reads, no LDS ----------------
__global__ __launch_bounds__(64, 4) void flash_kernel(
    const ushort* __restrict__ QF, const ushort* __restrict__ KF,
    const ushort* __restrict__ VF, const float* __restrict__ B2,
    float* __restrict__ Out)
{
  const int lane = threadIdx.x;
  const int quad = lane >> 4, ln = lane & 15;
  const int bid = blockIdx.x;
  const int bh  = bid % BHC;               // same bh -> same XCD (24 % 8 == 0)
  const int t16 = 127 - bid / BHC;         // heavy tiles first
  const int qrow = t16*16 + ln;            // this lane's q-row
  const int ktmax = t16 >> 2;              // last 64-key tile index

  const ushort* gK = KF + (long)bh * 131072;   // halves
  const ushort* gV = VF + (long)bh * 131072;
  const float*  gB = B2 + (long)bh * T_SEQ;

  // Q B-frags (x32 layout: d = quad*8+j per 32-slice), whole K-loop in regs
  half8_t bq[2];
  {
    const ushort* gQ = QF + ((long)bh*128 + t16) * 1024;
    bq[0] = *(const half8_t*)(gQ + lane*8);
    bq[1] = *(const half8_t*)(gQ + 512 + lane*8);
  }

  float m_i = -1e30f, l_i = 0.f;
  floatx4 acc[4];
#pragma unroll
  for (int nt = 0; nt < 4; nt++) acc[nt] = (floatx4){0.f,0.f,0.f,0.f};

  for (int kt = 0; kt <= ktmax; kt++) {
    const ushort* Kt = gK + (long)kt * 4096;   // tile kt, frag order
    const ushort* Vt = gV + (long)kt * 4096;

    // ---- S^T = K_aug·Q_aug^T (x32): st[mt][i] = S[q=ln][key=kt*64+mt*16+quad*4+i]
    floatx4 st[4];
#pragma unroll
    for (int mt = 0; mt < 4; mt++) {
      half8_t a0 = *(const half8_t*)(Kt + (mt*2    )*512 + lane*8);
      half8_t a1 = *(const half8_t*)(Kt + (mt*2 + 1)*512 + lane*8);
      floatx4 c = (floatx4){0.f,0.f,0.f,0.f};
      c = __builtin_amdgcn_mfma_f32_16x16x32_f16(a0, bq[0], c, 0, 0, 0);
      c = __builtin_amdgcn_mfma_f32_16x16x32_f16(a1, bq[1], c, 0, 0, 0);
      st[mt] = c;
    }

    // ---- bias + causal mask + online softmax (one q-row per lane) ----
    const bool diag = (kt == ktmax);
    float rowmax = -1e30f;
#pragma unroll
    for (int mt = 0; mt < 4; mt++) {
      float4 bb = *(const float4*)(gB + kt*64 + mt*16 + quad*4);  // quad-uniform
      float bv[4] = {bb.x, bb.y, bb.z, bb.w};
#pragma unroll
      for (int i = 0; i < 4; i++) {
        float v = st[mt][i] + bv[i];
        int key = kt*64 + mt*16 + quad*4 + i;
        if (diag && key > qrow) v = -1e30f;
        st[mt][i] = v;
        rowmax = fmaxf(rowmax, v);
      }
    }
    rowmax = fmaxf(rowmax, __shfl_xor(rowmax, 16));
    rowmax = fmaxf(rowmax, __shfl_xor(rowmax, 32));
    float mnew  = fmaxf(m_i, rowmax);
    float alpha = __expf(m_i - mnew);
    float psum = 0.f;
    half4_t pa[4];                        // C-regs are directly the x16 PV A-operand
#pragma unroll
    for (int mt = 0; mt < 4; mt++)
#pragma unroll
      for (int i = 0; i < 4; i++) {
        float p = __expf(st[mt][i] - mnew);
        psum += p;
        pa[mt][i] = (_Float16)p;
      }
    psum += __shfl_xor(psum, 16);
    psum += __shfl_xor(psum, 32);
    l_i = l_i * alpha + psum;
    m_i = mnew;

    float af[4];
#pragma unroll
    for (int i = 0; i < 4; i++) af[i] = __shfl(alpha, quad*4 + i);
#pragma unroll
    for (int nt = 0; nt < 4; nt++)
#pragma unroll
      for (int i = 0; i < 4; i++) acc[nt][i] *= af[i];

    // ---- O += P·V (x16; P stays in registers) ----
#pragma unroll
    for (int v2 = 0; v2 < 2; v2++)
#pragma unroll
      for (int nt = 0; nt < 4; nt++) {
        half8_t vv = *(const half8_t*)(Vt + (v2*4 + nt)*512 + lane*8);
        half4_t b0 = __builtin_shufflevector(vv, vv, 0,1,2,3);
        half4_t b1 = __builtin_shufflevector(vv, vv, 4,5,6,7);
        acc[nt] = __builtin_amdgcn_mfma_f32_16x16x16f16(pa[2*v2],   b0, acc[nt], 0, 0, 0);
        acc[nt] = __builtin_amdgcn_mfma_f32_16x16x16f16(pa[2*v2+1], b1, acc[nt], 0, 0, 0);
      }
  }

  // ---- epilogue ----
  float lr[4];
#pragma unroll
  for (int i = 0; i < 4; i++) lr[i] = 1.f / __shfl(l_i, quad*4 + i);
  const long obase = (long)bh*T_SEQ*64 + (long)(t16*16)*64;
#pragma unroll
  for (int i = 0; i < 4; i++)
#pragma unroll
    for (int nt = 0; nt < 4; nt++)
      Out[obase + (quad*4 + i)*64 + nt*16 + ln] = acc[nt][i] * lr[i];
}

extern "C" void kernel_launch(void* const* d_in, const int* in_sizes, int n_in,
                              void* d_out, int out_size, void* d_ws, size_t ws_size,
                              hipStream_t stream) {
  const float* Q     = (const float*)d_in[0];
  const float* K     = (const float*)d_in[1];
  const float* V     = (const float*)d_in[2];
  const float* dbias = (const float*)d_in[3];
  const float* W     = (const float*)d_in[4];
  const float* wstd  = (const float*)d_in[5];
  const float* wrec  = (const float*)d_in[6];
  const float* wdisc = (const float*)d_in[7];
  float* Out = (float*)d_out;

  const long NEL = (long)BHC * T_SEQ * 64;
  ushort* QF = (ushort*)d_ws;            // f16 x32-frag-order Q_aug (scales folded)
  ushort* KF = QF + NEL;                 // f16 x32-frag-order K_aug
  ushort* VF = KF + NEL;                 // f16 x16-frag-order V
  float*  B2 = (float*)(VF + NEL);       // premultiplied wd*dbias

  prep_kernel<<<BHC * NQT, 256, 0, stream>>>(Q, K, V, W, wstd, wrec, dbias, wdisc,
                                             QF, KF, VF, B2);
  flash_kernel<<<BHC * 128, 64, 0, stream>>>(QF, KF, VF, B2, Out);
}